// Round 1
// baseline (115.338 us; speedup 1.0000x reference)
//
#include <hip/hip_runtime.h>

// TF-IDF: out[b, v] = tf[b, v] * idf[v] / sum_v(tf[b, v] * idf[v])
//   x:   (512, 1024) int32 token ids in [0, 50257)
//   idf: (50257,) fp32
//   out: (512, 50257) fp32
//
// One block per batch row. Per-row histogram lives in LDS with two u16
// counts packed per u32 word (max count = SEQ = 1024 < 2^16, so the
// +65536 increment for odd vocab ids can never carry into the low half).
// Each output element is written exactly once -> no memset, no global
// atomics; kernel is bound by the 102.9 MB dense output write.

constexpr int VOCAB = 50257;
constexpr int SEQ = 1024;
constexpr int BATCH = 512;
constexpr int HWORDS = (VOCAB + 1) / 2;   // 25129 u32 words = 100,516 B LDS
constexpr int NTHREADS = 1024;            // == SEQ: one token per thread

__global__ __launch_bounds__(NTHREADS)
void tfidf_kernel(const int* __restrict__ x,
                  const float* __restrict__ idf,
                  float* __restrict__ out) {
    __shared__ unsigned int cnt[HWORDS];
    __shared__ float red[NTHREADS / 64];
    __shared__ float s_inv_n;

    const int b   = blockIdx.x;
    const int tid = threadIdx.x;

    // --- zero the packed histogram -------------------------------------
    for (int i = tid; i < HWORDS; i += NTHREADS) cnt[i] = 0u;
    __syncthreads();

    // --- histogram + normalizer ----------------------------------------
    const int tok = x[(size_t)b * SEQ + tid];        // one token per thread
    atomicAdd(&cnt[tok >> 1], (tok & 1) ? 65536u : 1u);

    // n = sum over tokens of idf[tok]  (== sum_v tf[v]*idf[v])
    float v = idf[tok];
    #pragma unroll
    for (int off = 32; off > 0; off >>= 1) v += __shfl_down(v, off, 64);
    if ((tid & 63) == 0) red[tid >> 6] = v;
    __syncthreads();
    if (tid == 0) {
        float n = 0.0f;
        #pragma unroll
        for (int w = 0; w < NTHREADS / 64; ++w) n += red[w];
        s_inv_n = 1.0f / n;
    }
    __syncthreads();
    const float inv_n = s_inv_n;

    // --- dense row write (coalesced scalar stores; rows start at odd
    //     float offsets so float2 would be 4B-misaligned) ----------------
    float* __restrict__ orow = out + (size_t)b * VOCAB;
    for (int vi = tid; vi < VOCAB; vi += NTHREADS) {
        const unsigned w = cnt[vi >> 1];
        const unsigned c = (vi & 1) ? (w >> 16) : (w & 0xffffu);
        orow[vi] = (float)c * idf[vi] * inv_n;
    }
}

extern "C" void kernel_launch(void* const* d_in, const int* in_sizes, int n_in,
                              void* d_out, int out_size, void* d_ws, size_t ws_size,
                              hipStream_t stream) {
    const int*   x   = (const int*)d_in[0];
    const float* idf = (const float*)d_in[1];
    float*       out = (float*)d_out;
    tfidf_kernel<<<dim3(BATCH), dim3(NTHREADS), 0, stream>>>(x, idf, out);
}